// Round 6
// baseline (172.394 us; speedup 1.0000x reference)
//
#include <hip/hip_runtime.h>
#include <math.h>

// Problem constants
#define IMGS 256
#define NANG 50
#define BATCH 4
#define NCNN 32
#define PIX (IMGS*IMGS)              // 65536
#define NPIX (BATCH*PIX)             // 262144

// Padded channel-last h1: [258][258][32] bf16 per batch
#define PROW 258
#define PPIX (PROW*PROW)
#define PB   (PPIX*NCNN)             // 2130048 bf16 per batch

// Workspace layout (float offsets)
#define OFF_FILT  0          // 51200 filtered sinogram (b,a,s)
#define OFF_W2BF  51200      // 9216 bf16 = 4608 floats ([tap][oc][ic])
#define OFF_H1P   55808      // 4*PB bf16 = 4260096 floats

static constexpr double PI_D = 3.14159265358979323846;

typedef unsigned short u16;
typedef unsigned int   u32;
typedef unsigned long long u64;
typedef __bf16 bfrag __attribute__((ext_vector_type(8)));
typedef float  ffrag __attribute__((ext_vector_type(4)));

__device__ __forceinline__ u16 f2bf(float f) {
    u32 u = __float_as_uint(f);
    u += 0x7fffu + ((u >> 16) & 1u);     // RNE
    return (u16)(u >> 16);
}

// =========== K_A: radon forward + ramp filter (fused), + w2->bf16 ===========
// blocks [0,200): one per (b,a): stage masked bf16 image in LDS, sample 256x256,
//   reduce, subtract x_sino, 511-tap ramp filter (taps computed in-block), -> FILT.
// blocks [200,218): w2 -> bf16 [tap][oc][ic]
#define RPITCH_D 131            // dwords per LDS image row (odd => bank-friendly)
__global__ __launch_bounds__(512) void k_A(const float* __restrict__ angles,
                                           const float* __restrict__ yprev,
                                           const float* __restrict__ xsino,
                                           const float* __restrict__ w2,
                                           float* __restrict__ ws) {
    __shared__ u16 limg[258 * 262];      // 135,192 B
    __shared__ float spart[512];
    __shared__ float staps[512];
    __shared__ float srow[256];
    int tid = threadIdx.x;
    int gid = blockIdx.x;
    if (gid >= 200) {                    // w2 conversion blocks
        int i = (gid - 200) * 512 + tid; // i = t*1024 + oc*32 + ic
        if (i < 9216) {
            int t = i >> 10, oc = (i >> 5) & 31, ic = i & 31;
            ((u16*)(ws + OFF_W2BF))[i] = f2bf(w2[(oc * 32 + ic) * 9 + t]);
        }
        return;
    }
    u32* l32 = (u32*)limg;
    int ra = gid;                        // b*50 + a
    int a = ra % NANG, b = ra / NANG;

    // ramp taps, closed form:
    // g[n]*512 = (-1)^n + S(n)/128, S(n)=sum_{k=1}^{255} k cos(k pi n/256)
    //          = (256cos(255t)-255cos(256t)-1)/(2(1-cos t)), t = pi n/256.
    if (tid < 511) {
        int d = tid - 255;
        int n = d < 0 ? -d : d;
        double g;
        if (n == 0) {
            g = 0.5;
        } else {
            double th = PI_D * (double)n / 256.0;
            double S = (256.0 * cos(255.0 * th) - 255.0 * cos(256.0 * th) - 1.0)
                       / (2.0 * (1.0 - cos(th)));
            double sign = (n & 1) ? -1.0 : 1.0;
            g = (sign + S / 128.0) / 512.0;
        }
        staps[tid] = (float)(g * PI_D / 100.0);   // fold pi/(2A), A=50
    }

    // zero image borders: dwords 0 & 129 of all 258 rows; dwords 1..128 of rows 0,257
    for (int z = tid; z < 772; z += 512) {
        int addr;
        if (z < 258)      addr = z * RPITCH_D;
        else if (z < 516) addr = (z - 258) * RPITCH_D + 129;
        else if (z < 644) addr = (z - 516) + 1;
        else              addr = 257 * RPITCH_D + (z - 644) + 1;
        l32[addr] = 0;
    }
    // stage interior: mask inline, fp32 -> bf16 (img row i -> row i+1, col j -> +2 u16)
    const float* __restrict__ src = yprev + b * PIX;
    for (int idx = tid; idx < 16384; idx += 512) {
        int r = idx >> 6, c4 = (idx & 63) << 2;
        float4 v = *(const float4*)(src + r * 256 + c4);
        float di = (float)r - 127.5f;
        float rr = di * di;
        float d0 = (float)c4 - 127.5f;
        v.x = (rr + d0 * d0 <= 16384.0f) ? v.x : 0.0f;
        v.y = (rr + (d0 + 1.0f) * (d0 + 1.0f) <= 16384.0f) ? v.y : 0.0f;
        v.z = (rr + (d0 + 2.0f) * (d0 + 2.0f) <= 16384.0f) ? v.z : 0.0f;
        v.w = (rr + (d0 + 3.0f) * (d0 + 3.0f) <= 16384.0f) ? v.w : 0.0f;
        u32 p0 = (u32)f2bf(v.x) | ((u32)f2bf(v.y) << 16);
        u32 p1 = (u32)f2bf(v.z) | ((u32)f2bf(v.w) << 16);
        int dw = (r + 1) * RPITCH_D + (c4 >> 1) + 1;
        l32[dw] = p0; l32[dw + 1] = p1;
    }
    __syncthreads();

    float a_ = angles[a];
    float cs = cosf(a_), sn = sinf(a_);
    int s = tid & 255, half = tid >> 8;
    float sc = (float)s - 127.5f;
    float t0c = 128.0f * (float)half - 127.5f;
    float rowv = sc * sn + t0c * cs + 127.5f;
    float colv = sc * cs - t0c * sn + 127.5f;
    float acc = 0.0f;
    #pragma unroll 4
    for (int it = 0; it < 128; ++it) {
        float fr = floorf(rowv), fc = floorf(colv);
        float wr = rowv - fr, wc = colv - fc;
        int i0 = (int)fr, j0 = (int)fc;
        bool valid = (rowv > -1.0f) & (rowv < 256.0f) & (colv > -1.0f) & (colv < 256.0f);
        int i0c = min(max(i0, -1), 255);
        int j0c = min(max(j0, -1), 255);
        int ca = j0c + 2;
        int ka = ca >> 1;
        int sh = (ca & 1) << 4;
        int dw = (i0c + 1) * RPITCH_D + ka;
        u32 A = l32[dw],            C = l32[dw + 1];
        u32 B = l32[dw + RPITCH_D], D = l32[dw + RPITCH_D + 1];
        u32 top = (u32)((((u64)C << 32) | (u64)A) >> sh);
        u32 bot = (u32)((((u64)D << 32) | (u64)B) >> sh);
        float tl = __uint_as_float(top << 16);
        float tr_ = __uint_as_float(top & 0xffff0000u);
        float bl = __uint_as_float(bot << 16);
        float br = __uint_as_float(bot & 0xffff0000u);
        float tv = tl + (tr_ - tl) * wc;
        float bv = bl + (br - bl) * wc;
        float sv = tv + (bv - tv) * wr;
        acc += valid ? sv : 0.0f;
        rowv += cs; colv -= sn;
    }
    spart[tid] = acc;
    __syncthreads();
    if (tid < 256)
        srow[tid] = spart[tid] + spart[tid + 256] - xsino[ra * 256 + tid];
    __syncthreads();
    {   // 511-tap filter, split 2 ways over taps
        float fa = 0.0f;
        int m0 = half * 128;
        #pragma unroll 8
        for (int m = m0; m < m0 + 128; ++m) fa += srow[m] * staps[s - m + 255];
        spart[tid] = fa;
    }
    __syncthreads();
    if (tid < 256)
        ws[OFF_FILT + ra * 256 + tid] = spart[tid] + spart[tid + 256];
}

// =========== K_B: backprojection + y_upd out + conv1 -> h1p (+borders) ===========
// One block per (b, 4-row tile). Computes y_upd rows y0-1..y0+4 into LDS,
// writes rows y0..y0+3 to dout[NPIX+..], then conv1 on those 4 rows.
__global__ __launch_bounds__(512) void k_B(const float* __restrict__ angles,
                                           const float* __restrict__ yprev,
                                           const float* __restrict__ yconc,
                                           const float* __restrict__ stepp,
                                           const float* __restrict__ w1,
                                           const float* __restrict__ b1,
                                           float* __restrict__ ws,
                                           float* __restrict__ dout) {
    __shared__ float sf[NANG * 256];     // 51.2 KB filtered sinogram (batch b)
    __shared__ float supd[6][258];       // y_upd rows y0-1..y0+4, col halo
    __shared__ float scs[NANG], ssn[NANG];
    int tid = threadIdx.x;
    int b = blockIdx.x >> 6, tile = blockIdx.x & 63;
    int y0 = tile << 2;

    for (int idx = tid; idx < NANG * 256; idx += 512)
        sf[idx] = ws[OFF_FILT + b * (NANG * 256) + idx];
    if (tid < NANG) {
        float a_ = angles[tid];
        scs[tid] = cosf(a_); ssn[tid] = sinf(a_);
    }
    if (tid < 12) supd[tid >> 1][(tid & 1) * 257] = 0.0f;
    // zero h1p borders (this block's share): 1028 border px * 16 dwords / 64 tiles
    {
        int px_i0 = tile * 17;
        if (tid < 272) {
            int px_i = px_i0 + (tid >> 4), dw = tid & 15;
            if (px_i < 1028) {
                int y, x;
                if (px_i < 516) { y = (px_i < 258) ? 0 : 257; x = px_i % 258; }
                else            { int j = px_i - 516; y = 1 + (j >> 1); x = (j & 1) * 257; }
                u32* p = (u32*)((u16*)(ws + OFF_H1P) + b * PB + (y * PROW + x) * NCNN);
                p[dw] = 0;
            }
        }
    }
    __syncthreads();

    float step = stepp[0];
    // backproject 6 rows x 256 cols
    for (int k = 0; k < 3; ++k) {
        int px = tid + k * 512;          // 0..1535
        int r = px >> 8, j = px & 255;
        int iy = y0 - 1 + r;
        float val = 0.0f;
        if ((unsigned)iy < 256u) {
            float yy = (float)iy - 127.5f, xx = (float)j - 127.5f;
            float acc = 0.0f;
            #pragma unroll 5
            for (int a = 0; a < NANG; ++a) {
                float idxf = xx * scs[a] + yy * ssn[a] + 127.5f;
                float fl = floorf(idxf);
                int i0 = (int)fl;
                i0 = min(max(i0, 0), 254);
                float w = idxf - (float)i0;
                float v = sf[a * 256 + i0] * (1.0f - w) + sf[a * 256 + i0 + 1] * w;
                acc += (idxf >= 0.0f && idxf <= 255.0f) ? v : 0.0f;
            }
            float m = (xx * xx + yy * yy <= 16384.0f) ? 1.0f : 0.0f;
            val = yprev[b * PIX + iy * 256 + j] + step * acc * m;
            if (r >= 1 && r <= 4)
                dout[NPIX + b * PIX + iy * 256 + j] = val;   // second output
        }
        supd[r][j + 1] = val;
    }
    __syncthreads();

    // conv1 (2->32) + relu on 4 rows -> h1p bf16 ch-last
    for (int k = 0; k < 2; ++k) {
        int px = tid + k * 512;          // 0..1023
        int rr = px >> 8, x = px & 255;
        int oy = y0 + rr;
        float v[18];
        #pragma unroll
        for (int ky = 0; ky < 3; ++ky)
            #pragma unroll
            for (int kx = 0; kx < 3; ++kx)
                v[ky * 3 + kx] = supd[rr + ky][x + kx];
        const float* __restrict__ in1 = yconc + b * PIX;
        #pragma unroll
        for (int ky = 0; ky < 3; ++ky)
            #pragma unroll
            for (int kx = 0; kx < 3; ++kx) {
                int yy = oy + ky - 1, xx = x + kx - 1;
                v[9 + ky * 3 + kx] =
                    ((unsigned)yy < 256u && (unsigned)xx < 256u) ? in1[yy * 256 + xx] : 0.0f;
            }
        u32 pk[16];
        #pragma unroll
        for (int oc2 = 0; oc2 < 16; ++oc2) {
            float a0 = b1[2 * oc2], a1 = b1[2 * oc2 + 1];
            const float* wp = w1 + (2 * oc2) * 18;
            #pragma unroll
            for (int t = 0; t < 18; ++t) { a0 += v[t] * wp[t]; a1 += v[t] * wp[18 + t]; }
            a0 = fmaxf(a0, 0.0f); a1 = fmaxf(a1, 0.0f);
            pk[oc2] = (u32)f2bf(a0) | ((u32)f2bf(a1) << 16);
        }
        uint4* o4 = (uint4*)((u16*)(ws + OFF_H1P) + b * PB + ((oy + 1) * PROW + (x + 1)) * NCNN);
        #pragma unroll
        for (int q = 0; q < 4; ++q)
            o4[q] = make_uint4(pk[4 * q], pk[4 * q + 1], pk[4 * q + 2], pk[4 * q + 3]);
    }
}

// =========== K_C: conv2 (MFMA) -> LDS h2 tile + conv3 -> out ===========
// One block per (b, 4-row tile). conv2 computes h2 rows y0-1..y0+4 (6 rows) into
// LDS [6][258 px][34 u16] (px stride 17 dw, odd); conv3 consumes -> dout.
#define H2PITCH 34               // u16 per px slot (32 ch + 2 pad)
__global__ __launch_bounds__(512) void k_C(const float* __restrict__ b2,
                                           const float* __restrict__ w3,
                                           const float* __restrict__ b3,
                                           float* __restrict__ ws,
                                           float* __restrict__ dout) {
    __shared__ u16 sh2[6 * 258 * H2PITCH];   // 105,264 B
    __shared__ float sw[288];                // sw[t*32+ic] = w3[ic*9+t]
    u32* l32 = (u32*)sh2;
    int tid = threadIdx.x;
    int b = blockIdx.x >> 6, tile = blockIdx.x & 63;
    int y0 = tile << 2;

    for (int idx = tid; idx < 288; idx += 512)
        sw[idx] = w3[(idx & 31) * 9 + (idx >> 5)];
    // zero border px columns (stored px 0 and 257) of all 6 rows
    for (int idx = tid; idx < 6 * 2 * 17; idx += 512) {
        int r = idx / 34, rem = idx % 34;
        int col = (rem < 17) ? 0 : 257, dw = rem % 17;
        l32[(r * 258 + col) * 17 + dw] = 0;
    }
    // zero out-of-image rows (edge tiles only)
    #pragma unroll
    for (int r = 0; r < 6; ++r) {
        int hy = y0 - 1 + r;
        if (hy < 0 || hy > 255)
            for (int idx = tid; idx < 258 * 17; idx += 512)
                l32[r * 258 * 17 + idx] = 0;
    }
    __syncthreads();

    // ---- conv2 MFMA: 96 (row, 16px) tiles over 8 waves ----
    const u16* __restrict__ w2bf = (const u16*)(ws + OFF_W2BF);
    const u16* __restrict__ h1b  = (const u16*)(ws + OFF_H1P) + b * PB;
    int wave = tid >> 6, lane = tid & 63;
    int m = lane & 15, quad = lane >> 4;
    bfrag Bf[9][2];
    #pragma unroll
    for (int t = 0; t < 9; ++t) {
        const u16* wp = w2bf + t * 1024 + m * 32 + quad * 8;
        Bf[t][0] = *(const bfrag*)(wp);
        Bf[t][1] = *(const bfrag*)(wp + 16 * 32);
    }
    float bias0 = b2[m], bias1 = b2[m + 16];
    #pragma unroll
    for (int k = 0; k < 12; ++k) {
        int tl = wave + (k << 3);        // 0..95
        int ridx = tl >> 4, xt = tl & 15;
        int hy = y0 - 1 + ridx;
        if ((unsigned)hy < 256u) {
            int xs = xt << 4;
            bfrag Af[9];
            #pragma unroll
            for (int t = 0; t < 9; ++t) {
                int ty = t / 3, tx = t % 3;
                const u16* ap = h1b + ((hy + ty) * PROW + xs + m + tx) * NCNN + quad * 8;
                Af[t] = *(const bfrag*)ap;
            }
            ffrag c0 = {0.f, 0.f, 0.f, 0.f}, c1 = {0.f, 0.f, 0.f, 0.f};
            #pragma unroll
            for (int t = 0; t < 9; ++t) {
                c0 = __builtin_amdgcn_mfma_f32_16x16x32_bf16(Af[t], Bf[t][0], c0, 0, 0, 0);
                c1 = __builtin_amdgcn_mfma_f32_16x16x32_bf16(Af[t], Bf[t][1], c1, 0, 0, 0);
            }
            #pragma unroll
            for (int r = 0; r < 4; ++r) {
                int px = xs + quad * 4 + r;
                u16* op = sh2 + (ridx * 258 + px + 1) * H2PITCH;
                op[m]      = f2bf(fmaxf(c0[r] + bias0, 0.0f));
                op[m + 16] = f2bf(fmaxf(c1[r] + bias1, 0.0f));
            }
        }
    }
    __syncthreads();

    // ---- conv3 (32->1): 2 adjacent px per thread ----
    {
        int pid = tid * 2;               // 0..1022
        int rr = pid >> 8, x = pid & 255;
        int oy = y0 + rr;
        float bias = b3[0];
        float a0 = bias, a1 = bias;
        #pragma unroll
        for (int ky = 0; ky < 3; ++ky) {
            #pragma unroll
            for (int cx = 0; cx < 4; ++cx) {
                const u32* q = l32 + ((rr + ky) * 258 + x + cx) * 17;
                #pragma unroll
                for (int kd = 0; kd < 16; ++kd) {
                    u32 wv = q[kd];
                    float f0 = __uint_as_float(wv << 16);
                    float f1 = __uint_as_float(wv & 0xffff0000u);
                    int ch = kd * 2;
                    if (cx < 3) {
                        int t = ky * 3 + cx;
                        a0 += f0 * sw[t * 32 + ch] + f1 * sw[t * 32 + ch + 1];
                    }
                    if (cx > 0) {
                        int t = ky * 3 + cx - 1;
                        a1 += f0 * sw[t * 32 + ch] + f1 * sw[t * 32 + ch + 1];
                    }
                }
            }
        }
        float* op = dout + b * PIX + oy * 256 + x;
        op[0] = a0; op[1] = a1;
    }
}

extern "C" void kernel_launch(void* const* d_in, const int* in_sizes, int n_in,
                              void* d_out, int out_size, void* d_ws, size_t ws_size,
                              hipStream_t stream) {
    const float* xsino  = (const float*)d_in[0];
    const float* yprev  = (const float*)d_in[1];
    const float* yconc  = (const float*)d_in[2];
    const float* angles = (const float*)d_in[3];
    const float* stepp  = (const float*)d_in[4];
    const float* w1 = (const float*)d_in[5];
    const float* b1 = (const float*)d_in[6];
    const float* w2 = (const float*)d_in[7];
    const float* b2 = (const float*)d_in[8];
    const float* w3 = (const float*)d_in[9];
    const float* b3 = (const float*)d_in[10];
    float* out = (float*)d_out;
    float* ws  = (float*)d_ws;

    k_A<<<218, 512, 0, stream>>>(angles, yprev, xsino, w2, ws);
    k_B<<<BATCH * 64, 512, 0, stream>>>(angles, yprev, yconc, stepp, w1, b1, ws, out);
    k_C<<<BATCH * 64, 512, 0, stream>>>(b2, w3, b3, ws, out);
}

// Round 7
// 157.552 us; speedup vs baseline: 1.0942x; 1.0942x over previous
//
#include <hip/hip_runtime.h>
#include <math.h>

// Problem constants
#define IMGS 256
#define NANG 50
#define BATCH 4
#define NCNN 32
#define PIX (IMGS*IMGS)              // 65536
#define NPIX (BATCH*PIX)             // 262144

// Padded channel-last h1: [258][258][32] bf16 per batch
#define PROW 258
#define PPIX (PROW*PROW)
#define PB   (PPIX*NCNN)             // 2130048 bf16 per batch

// Workspace layout (float offsets)
#define OFF_FILT  0          // 51200 filtered sinogram (b,a,s)
#define OFF_W2BF  51200      // 9216 bf16 = 4608 floats ([tap][oc][ic])
#define OFF_H1P   55808      // 4*PB bf16 = 4260096 floats

static constexpr double PI_D = 3.14159265358979323846;

typedef unsigned short u16;
typedef unsigned int   u32;
typedef unsigned long long u64;
typedef __bf16 bfrag __attribute__((ext_vector_type(8)));
typedef float  ffrag __attribute__((ext_vector_type(4)));

__device__ __forceinline__ u16 f2bf(float f) {
    u32 u = __float_as_uint(f);
    u += 0x7fffu + ((u >> 16) & 1u);     // RNE
    return (u16)(u >> 16);
}

// =========== K_A: radon forward + ramp filter (fused), + w2->bf16 ===========
// blocks [0,200): one per (b,a), 1024 threads (16 waves/CU for latency hiding).
// blocks [200,209): w2 -> bf16 [tap][oc][ic]
#define RPITCH_D 131            // dwords per LDS image row (odd => bank-friendly)
__global__ __launch_bounds__(1024) void k_A(const float* __restrict__ angles,
                                            const float* __restrict__ yprev,
                                            const float* __restrict__ xsino,
                                            const float* __restrict__ w2,
                                            float* __restrict__ ws) {
    __shared__ u16 limg[258 * 262];      // 135,192 B
    __shared__ float spart[1024];
    __shared__ float staps[512];
    __shared__ float srow[256];
    int tid = threadIdx.x;
    int gid = blockIdx.x;
    if (gid >= 200) {                    // w2 conversion blocks
        int i = (gid - 200) * 1024 + tid;
        if (i < 9216) {
            int t = i >> 10, oc = (i >> 5) & 31, ic = i & 31;
            ((u16*)(ws + OFF_W2BF))[i] = f2bf(w2[(oc * 32 + ic) * 9 + t]);
        }
        return;
    }
    u32* l32 = (u32*)limg;
    int ra = gid;                        // b*50 + a
    int a = ra % NANG, b = ra / NANG;

    // ramp taps, closed form:
    // g[n]*512 = (-1)^n + S(n)/128, S(n)=sum_{k=1}^{255} k cos(k pi n/256)
    //          = (256cos(255t)-255cos(256t)-1)/(2(1-cos t)), t = pi n/256.
    if (tid < 511) {
        int d = tid - 255;
        int n = d < 0 ? -d : d;
        double g;
        if (n == 0) {
            g = 0.5;
        } else {
            double th = PI_D * (double)n / 256.0;
            double S = (256.0 * cos(255.0 * th) - 255.0 * cos(256.0 * th) - 1.0)
                       / (2.0 * (1.0 - cos(th)));
            double sign = (n & 1) ? -1.0 : 1.0;
            g = (sign + S / 128.0) / 512.0;
        }
        staps[tid] = (float)(g * PI_D / 100.0);   // fold pi/(2A), A=50
    }

    // zero image borders
    for (int z = tid; z < 772; z += 1024) {
        int addr;
        if (z < 258)      addr = z * RPITCH_D;
        else if (z < 516) addr = (z - 258) * RPITCH_D + 129;
        else if (z < 644) addr = (z - 516) + 1;
        else              addr = 257 * RPITCH_D + (z - 644) + 1;
        l32[addr] = 0;
    }
    // stage interior: mask inline, fp32 -> bf16
    const float* __restrict__ src = yprev + b * PIX;
    for (int idx = tid; idx < 16384; idx += 1024) {
        int r = idx >> 6, c4 = (idx & 63) << 2;
        float4 v = *(const float4*)(src + r * 256 + c4);
        float di = (float)r - 127.5f;
        float rr = di * di;
        float d0 = (float)c4 - 127.5f;
        v.x = (rr + d0 * d0 <= 16384.0f) ? v.x : 0.0f;
        v.y = (rr + (d0 + 1.0f) * (d0 + 1.0f) <= 16384.0f) ? v.y : 0.0f;
        v.z = (rr + (d0 + 2.0f) * (d0 + 2.0f) <= 16384.0f) ? v.z : 0.0f;
        v.w = (rr + (d0 + 3.0f) * (d0 + 3.0f) <= 16384.0f) ? v.w : 0.0f;
        u32 p0 = (u32)f2bf(v.x) | ((u32)f2bf(v.y) << 16);
        u32 p1 = (u32)f2bf(v.z) | ((u32)f2bf(v.w) << 16);
        int dw = (r + 1) * RPITCH_D + (c4 >> 1) + 1;
        l32[dw] = p0; l32[dw + 1] = p1;
    }
    __syncthreads();

    float a_ = angles[a];
    float cs = cosf(a_), sn = sinf(a_);
    int s = tid & 255, q = tid >> 8;     // q in [0,4): t-quarter
    float sc = (float)s - 127.5f;
    float t0c = 64.0f * (float)q - 127.5f;
    float rowv = sc * sn + t0c * cs + 127.5f;
    float colv = sc * cs - t0c * sn + 127.5f;
    float acc = 0.0f;
    #pragma unroll 4
    for (int it = 0; it < 64; ++it) {
        float fr = floorf(rowv), fc = floorf(colv);
        float wr = rowv - fr, wc = colv - fc;
        int i0 = (int)fr, j0 = (int)fc;
        bool valid = (rowv > -1.0f) & (rowv < 256.0f) & (colv > -1.0f) & (colv < 256.0f);
        int i0c = min(max(i0, -1), 255);
        int j0c = min(max(j0, -1), 255);
        int ca = j0c + 2;
        int ka = ca >> 1;
        int sh = (ca & 1) << 4;
        int dw = (i0c + 1) * RPITCH_D + ka;
        u32 A = l32[dw],            C = l32[dw + 1];
        u32 B = l32[dw + RPITCH_D], D = l32[dw + RPITCH_D + 1];
        u32 top = (u32)((((u64)C << 32) | (u64)A) >> sh);
        u32 bot = (u32)((((u64)D << 32) | (u64)B) >> sh);
        float tl = __uint_as_float(top << 16);
        float tr_ = __uint_as_float(top & 0xffff0000u);
        float bl = __uint_as_float(bot << 16);
        float br = __uint_as_float(bot & 0xffff0000u);
        float tv = tl + (tr_ - tl) * wc;
        float bv = bl + (br - bl) * wc;
        float sv = tv + (bv - tv) * wr;
        acc += valid ? sv : 0.0f;
        rowv += cs; colv -= sn;
    }
    spart[tid] = acc;
    __syncthreads();
    if (tid < 256)
        srow[tid] = spart[tid] + spart[tid + 256] + spart[tid + 512] + spart[tid + 768]
                    - xsino[ra * 256 + tid];
    __syncthreads();
    {   // 511-tap filter, split 4 ways over taps
        float fa = 0.0f;
        int m0 = q * 64;
        #pragma unroll 8
        for (int m = m0; m < m0 + 64; ++m) fa += srow[m] * staps[s - m + 255];
        spart[tid] = fa;
    }
    __syncthreads();
    if (tid < 256)
        ws[OFF_FILT + ra * 256 + tid] =
            spart[tid] + spart[tid + 256] + spart[tid + 512] + spart[tid + 768];
}

// =========== K_B: backprojection + y_upd out + conv1 -> h1p ===========
// One block per (b, 4-row tile). 512 thr, 2 blocks/CU target.
// Backproj: 3 interleaved row-chains per thread. Conv1: wave-stationary oc
// (each wave owns 4 oc, 72 weights in VGPRs); y_concat staged in LDS.
__global__ __launch_bounds__(512, 4) void k_B(const float* __restrict__ angles,
                                              const float* __restrict__ yprev,
                                              const float* __restrict__ yconc,
                                              const float* __restrict__ stepp,
                                              const float* __restrict__ w1,
                                              const float* __restrict__ b1,
                                              float* __restrict__ ws,
                                              float* __restrict__ dout) {
    __shared__ float sf[NANG * 256];     // 51.2 KB filtered sinogram (batch b)
    __shared__ float supd[6][258];       // y_upd rows y0-1..y0+4 (+col halo)
    __shared__ float sy2[6][258];        // y_concat rows y0-1..y0+4 (+col halo)
    __shared__ float scs[NANG], ssn[NANG];
    int tid = threadIdx.x;
    int b = blockIdx.x >> 6, tile = blockIdx.x & 63;
    int y0 = tile << 2;

    for (int idx = tid; idx < NANG * 256; idx += 512)
        sf[idx] = ws[OFF_FILT + b * (NANG * 256) + idx];
    if (tid < NANG) {
        float a_ = angles[tid];
        scs[tid] = cosf(a_); ssn[tid] = sinf(a_);
    }
    if (tid < 12) supd[tid >> 1][(tid & 1) * 257] = 0.0f;
    // stage y_concat halo tile
    for (int idx = tid; idx < 6 * 258; idx += 512) {
        int r = idx / 258, x = idx % 258;
        int iy = y0 - 1 + r, ix = x - 1;
        sy2[r][x] = ((unsigned)iy < 256u && (unsigned)ix < 256u)
                        ? yconc[b * PIX + iy * 256 + ix] : 0.0f;
    }
    // zero h1p borders (this block's share)
    {
        if (tid < 272) {
            int px_i = tile * 17 + (tid >> 4), dw = tid & 15;
            if (px_i < 1028) {
                int y, x;
                if (px_i < 516) { y = (px_i < 258) ? 0 : 257; x = px_i % 258; }
                else            { int j = px_i - 516; y = 1 + (j >> 1); x = (j & 1) * 257; }
                u32* p = (u32*)((u16*)(ws + OFF_H1P) + b * PB + (y * PROW + x) * NCNN);
                p[dw] = 0;
            }
        }
    }
    __syncthreads();

    float step = stepp[0];
    // backproject 6 rows x 256 cols: thread owns col j, rows r0, r0+2, r0+4
    {
        int j = tid & 255, r0 = tid >> 8;         // r0 in {0,1}
        float xx = (float)j - 127.5f;
        float yy0 = (float)(y0 - 1 + r0) - 127.5f;
        float acc[3] = {0.0f, 0.0f, 0.0f};
        for (int a = 0; a < NANG; ++a) {
            float cs = scs[a], sn = ssn[a];
            float sn2 = sn + sn;
            float f0 = xx * cs + yy0 * sn + 127.5f;
            float idxf[3] = {f0, f0 + sn2, f0 + sn2 + sn2};
            #pragma unroll
            for (int k = 0; k < 3; ++k) {
                float fl = floorf(idxf[k]);
                int i0 = (int)fl;
                i0 = min(max(i0, 0), 254);
                float w = idxf[k] - (float)i0;
                float v = sf[a * 256 + i0] * (1.0f - w) + sf[a * 256 + i0 + 1] * w;
                acc[k] += (idxf[k] >= 0.0f && idxf[k] <= 255.0f) ? v : 0.0f;
            }
        }
        #pragma unroll
        for (int k = 0; k < 3; ++k) {
            int r = r0 + 2 * k;
            int iy = y0 - 1 + r;
            float val = 0.0f;
            if ((unsigned)iy < 256u) {
                float yy = (float)iy - 127.5f;
                float m = (xx * xx + yy * yy <= 16384.0f) ? 1.0f : 0.0f;
                val = yprev[b * PIX + iy * 256 + j] + step * acc[k] * m;
                if (r >= 1 && r <= 4)
                    dout[NPIX + b * PIX + iy * 256 + j] = val;   // second output
            }
            supd[r][j + 1] = val;
        }
    }
    __syncthreads();

    // conv1 (2->32) + relu: wave w owns oc [4w, 4w+4); weights in VGPRs
    {
        int wave = tid >> 6, lane = tid & 63;
        int oc0 = wave * 4;
        float W[72];
        const float4* wsrc = (const float4*)(w1 + oc0 * 18);
        #pragma unroll
        for (int i = 0; i < 18; ++i) ((float4*)W)[i] = wsrc[i];
        float bb0 = b1[oc0], bb1 = b1[oc0 + 1], bb2 = b1[oc0 + 2], bb3 = b1[oc0 + 3];
        u16* h1base = (u16*)(ws + OFF_H1P) + b * PB;
        for (int it = 0; it < 16; ++it) {
            int px = it * 64 + lane;
            int rr = px >> 8, x = px & 255;
            int oy = y0 + rr;
            float v[18];
            #pragma unroll
            for (int ky = 0; ky < 3; ++ky)
                #pragma unroll
                for (int kx = 0; kx < 3; ++kx) {
                    v[ky * 3 + kx]     = supd[rr + ky][x + kx];
                    v[9 + ky * 3 + kx] = sy2[rr + ky][x + kx];
                }
            float a0 = bb0, a1 = bb1, a2 = bb2, a3 = bb3;
            #pragma unroll
            for (int t = 0; t < 18; ++t) {
                a0 += v[t] * W[t];
                a1 += v[t] * W[18 + t];
                a2 += v[t] * W[36 + t];
                a3 += v[t] * W[54 + t];
            }
            u32 p0 = (u32)f2bf(fmaxf(a0, 0.0f)) | ((u32)f2bf(fmaxf(a1, 0.0f)) << 16);
            u32 p1 = (u32)f2bf(fmaxf(a2, 0.0f)) | ((u32)f2bf(fmaxf(a3, 0.0f)) << 16);
            u32* op = (u32*)(h1base + ((oy + 1) * PROW + (x + 1)) * NCNN + oc0);
            op[0] = p0; op[1] = p1;
        }
    }
}

// =========== K_C: conv2 (MFMA) -> LDS h2 tile + conv3 -> out ===========
// One block per (b, 4-row tile), 1024 threads (16 waves).
#define H2PITCH 34               // u16 per px slot (32 ch + 2 pad) = 17 dwords
__global__ __launch_bounds__(1024) void k_C(const float* __restrict__ b2,
                                            const float* __restrict__ w3,
                                            const float* __restrict__ b3,
                                            float* __restrict__ ws,
                                            float* __restrict__ dout) {
    __shared__ u16 sh2[6 * 258 * H2PITCH];   // 105,264 B
    __shared__ u32 swp[9 * 16];              // w3 packed bf16 ch-pairs [t][kd]
    u32* l32 = (u32*)sh2;
    int tid = threadIdx.x;
    int b = blockIdx.x >> 6, tile = blockIdx.x & 63;
    int y0 = tile << 2;

    if (tid < 144) {
        int t = tid >> 4, kd = tid & 15;
        swp[tid] = (u32)f2bf(w3[(2 * kd) * 9 + t]) | ((u32)f2bf(w3[(2 * kd + 1) * 9 + t]) << 16);
    }
    // zero border px columns (stored px 0 and 257) of all 6 rows
    if (tid < 204) {
        int r = tid / 34, rem = tid % 34;
        int col = (rem < 17) ? 0 : 257, dw = rem % 17;
        l32[(r * 258 + col) * 17 + dw] = 0;
    }
    // zero out-of-image rows (edge tiles only)
    #pragma unroll
    for (int r = 0; r < 6; ++r) {
        int hy = y0 - 1 + r;
        if (hy < 0 || hy > 255)
            for (int idx = tid; idx < 258 * 17; idx += 1024)
                l32[r * 258 * 17 + idx] = 0;
    }
    __syncthreads();

    // ---- conv2 MFMA: 96 (row, 16px) tiles over 16 waves ----
    const u16* __restrict__ w2bf = (const u16*)(ws + OFF_W2BF);
    const u16* __restrict__ h1b  = (const u16*)(ws + OFF_H1P) + b * PB;
    int wave = tid >> 6, lane = tid & 63;
    int m = lane & 15, quad = lane >> 4;
    bfrag Bf[9][2];
    #pragma unroll
    for (int t = 0; t < 9; ++t) {
        const u16* wp = w2bf + t * 1024 + m * 32 + quad * 8;
        Bf[t][0] = *(const bfrag*)(wp);
        Bf[t][1] = *(const bfrag*)(wp + 16 * 32);
    }
    float bias0 = b2[m], bias1 = b2[m + 16];
    #pragma unroll
    for (int k = 0; k < 6; ++k) {
        int tl = wave + (k << 4);        // 0..95
        int ridx = tl >> 4, xt = tl & 15;
        int hy = y0 - 1 + ridx;
        bool valid = (unsigned)hy < 256u;
        int hyc = min(max(hy, 0), 255);
        int xs = xt << 4;
        ffrag c0 = {0.f, 0.f, 0.f, 0.f}, c1 = {0.f, 0.f, 0.f, 0.f};
        #pragma unroll
        for (int g = 0; g < 3; ++g) {    // rolling 3-tap groups (reg pressure)
            bfrag Af[3];
            #pragma unroll
            for (int tt = 0; tt < 3; ++tt) {
                int t = g * 3 + tt;
                int ty = t / 3, tx = t % 3;
                Af[tt] = *(const bfrag*)(h1b + ((hyc + ty) * PROW + xs + m + tx) * NCNN + quad * 8);
            }
            #pragma unroll
            for (int tt = 0; tt < 3; ++tt) {
                c0 = __builtin_amdgcn_mfma_f32_16x16x32_bf16(Af[tt], Bf[g * 3 + tt][0], c0, 0, 0, 0);
                c1 = __builtin_amdgcn_mfma_f32_16x16x32_bf16(Af[tt], Bf[g * 3 + tt][1], c1, 0, 0, 0);
            }
        }
        if (valid) {
            #pragma unroll
            for (int r = 0; r < 4; ++r) {
                int px = xs + quad * 4 + r;
                u16* op = sh2 + (ridx * 258 + px + 1) * H2PITCH;
                op[m]      = f2bf(fmaxf(c0[r] + bias0, 0.0f));
                op[m + 16] = f2bf(fmaxf(c1[r] + bias1, 0.0f));
            }
        }
    }
    __syncthreads();

    // ---- conv3 (32->1): one px per thread; w3 packed pairs in VGPRs ----
    {
        uint4 WP[9];
        #pragma unroll
        for (int t = 0; t < 9; ++t) WP[t] = ((const uint4*)swp)[t * 4 + 0],
                                    WP[t] = *(const uint4*)(swp + t * 16);   // full 16 dwords read below
        // hold all 36 weight dwords:
        u32 Wd[36];
        #pragma unroll
        for (int i = 0; i < 36; ++i) Wd[i] = swp[(i / 4) * 16 + (i & 3)];
        // NOTE: Wd holds only dwords 0..3 of each tap; remaining read uniform below.
        (void)WP;
        int rr = tid >> 8, x = tid & 255;
        int oy = y0 + rr;
        float acc = b3[0];
        #pragma unroll
        for (int ky = 0; ky < 3; ++ky) {
            #pragma unroll
            for (int cx = 0; cx < 3; ++cx) {
                int t = ky * 3 + cx;
                const u32* q = l32 + ((rr + ky) * 258 + x + cx) * 17;
                #pragma unroll
                for (int kd = 0; kd < 16; ++kd) {
                    u32 hv = q[kd];
                    u32 wv = (kd < 4) ? Wd[t * 4 + kd] : swp[t * 16 + kd];
                    float h0 = __uint_as_float(hv << 16);
                    float h1 = __uint_as_float(hv & 0xffff0000u);
                    float w0 = __uint_as_float(wv << 16);
                    float w1_ = __uint_as_float(wv & 0xffff0000u);
                    acc += h0 * w0 + h1 * w1_;
                }
            }
        }
        dout[b * PIX + oy * 256 + x] = acc;    // first output
    }
}

extern "C" void kernel_launch(void* const* d_in, const int* in_sizes, int n_in,
                              void* d_out, int out_size, void* d_ws, size_t ws_size,
                              hipStream_t stream) {
    const float* xsino  = (const float*)d_in[0];
    const float* yprev  = (const float*)d_in[1];
    const float* yconc  = (const float*)d_in[2];
    const float* angles = (const float*)d_in[3];
    const float* stepp  = (const float*)d_in[4];
    const float* w1 = (const float*)d_in[5];
    const float* b1 = (const float*)d_in[6];
    const float* w2 = (const float*)d_in[7];
    const float* b2 = (const float*)d_in[8];
    const float* w3 = (const float*)d_in[9];
    const float* b3 = (const float*)d_in[10];
    float* out = (float*)d_out;
    float* ws  = (float*)d_ws;

    k_A<<<209, 1024, 0, stream>>>(angles, yprev, xsino, w2, ws);
    k_B<<<BATCH * 64, 512, 0, stream>>>(angles, yprev, yconc, stepp, w1, b1, ws, out);
    k_C<<<BATCH * 64, 1024, 0, stream>>>(b2, w3, b3, ws, out);
}

// Round 8
// 154.692 us; speedup vs baseline: 1.1144x; 1.0185x over previous
//
#include <hip/hip_runtime.h>
#include <math.h>

// Problem constants
#define IMGS 256
#define NANG 50
#define BATCH 4
#define NCNN 32
#define PIX (IMGS*IMGS)              // 65536
#define NPIX (BATCH*PIX)             // 262144

// Padded channel-last h1: [258][258][32] bf16 per batch
#define PROW 258
#define PPIX (PROW*PROW)
#define PB   (PPIX*NCNN)             // 2130048 bf16 per batch

// Workspace layout (float offsets)
#define OFF_FILT  0          // 51200 filtered sinogram (b,a,s)
#define OFF_W2BF  51200      // 9216 bf16 = 4608 floats ([tap][oc][ic])
#define OFF_H1P   55808      // 4*PB bf16 = 4260096 floats

static constexpr double PI_D = 3.14159265358979323846;

typedef unsigned short u16;
typedef unsigned int   u32;
typedef unsigned long long u64;
typedef __bf16 bfrag __attribute__((ext_vector_type(8)));
typedef float  ffrag __attribute__((ext_vector_type(4)));

__device__ __forceinline__ u16 f2bf(float f) {
    u32 u = __float_as_uint(f);
    u += 0x7fffu + ((u >> 16) & 1u);     // RNE
    return (u16)(u >> 16);
}

// =========== K_A: radon forward + ramp filter (fused), + w2->bf16 ===========
// blocks [0,200): one per (b,a), 1024 threads. Sampling uses 8x8 (s x t) lane
// patches so LDS bank spread is 2D (bounded ~2-4-way for ANY angle; the old
// 64x1 line layout hit 32-64-way conflicts when (sn*131+cs/2) mod 32 ~ small
// rationals, making straggler angle-blocks dominate).
// blocks [200,209): w2 -> bf16 [tap][oc][ic]
#define RPITCH_D 131            // dwords per LDS image row (odd => bank-friendly)
__global__ __launch_bounds__(1024, 4) void k_A(const float* __restrict__ angles,
                                               const float* __restrict__ yprev,
                                               const float* __restrict__ xsino,
                                               const float* __restrict__ w2,
                                               float* __restrict__ ws) {
    __shared__ u16 limg[258 * 262];      // 135,192 B
    __shared__ float spart[1024];
    __shared__ float staps[512];
    __shared__ float srow[256];
    int tid = threadIdx.x;
    int gid = blockIdx.x;
    if (gid >= 200) {                    // w2 conversion blocks
        int i = (gid - 200) * 1024 + tid;
        if (i < 9216) {
            int t = i >> 10, oc = (i >> 5) & 31, ic = i & 31;
            ((u16*)(ws + OFF_W2BF))[i] = f2bf(w2[(oc * 32 + ic) * 9 + t]);
        }
        return;
    }
    u32* l32 = (u32*)limg;
    int ra = gid;                        // b*50 + a
    int a = ra % NANG, b = ra / NANG;

    // ramp taps, closed form:
    // g[n]*512 = (-1)^n + S(n)/128, S(n)=sum_{k=1}^{255} k cos(k pi n/256)
    //          = (256cos(255t)-255cos(256t)-1)/(2(1-cos t)), t = pi n/256.
    if (tid < 511) {
        int d = tid - 255;
        int n = d < 0 ? -d : d;
        double g;
        if (n == 0) {
            g = 0.5;
        } else {
            double th = PI_D * (double)n / 256.0;
            double S = (256.0 * cos(255.0 * th) - 255.0 * cos(256.0 * th) - 1.0)
                       / (2.0 * (1.0 - cos(th)));
            double sign = (n & 1) ? -1.0 : 1.0;
            g = (sign + S / 128.0) / 512.0;
        }
        staps[tid] = (float)(g * PI_D / 100.0);   // fold pi/(2A), A=50
    }

    // zero image borders
    for (int z = tid; z < 772; z += 1024) {
        int addr;
        if (z < 258)      addr = z * RPITCH_D;
        else if (z < 516) addr = (z - 258) * RPITCH_D + 129;
        else if (z < 644) addr = (z - 516) + 1;
        else              addr = 257 * RPITCH_D + (z - 644) + 1;
        l32[addr] = 0;
    }
    // stage interior: mask inline, fp32 -> bf16
    const float* __restrict__ src = yprev + b * PIX;
    for (int idx = tid; idx < 16384; idx += 1024) {
        int r = idx >> 6, c4 = (idx & 63) << 2;
        float4 v = *(const float4*)(src + r * 256 + c4);
        float di = (float)r - 127.5f;
        float rr = di * di;
        float d0 = (float)c4 - 127.5f;
        v.x = (rr + d0 * d0 <= 16384.0f) ? v.x : 0.0f;
        v.y = (rr + (d0 + 1.0f) * (d0 + 1.0f) <= 16384.0f) ? v.y : 0.0f;
        v.z = (rr + (d0 + 2.0f) * (d0 + 2.0f) <= 16384.0f) ? v.z : 0.0f;
        v.w = (rr + (d0 + 3.0f) * (d0 + 3.0f) <= 16384.0f) ? v.w : 0.0f;
        u32 p0 = (u32)f2bf(v.x) | ((u32)f2bf(v.y) << 16);
        u32 p1 = (u32)f2bf(v.z) | ((u32)f2bf(v.w) << 16);
        int dw = (r + 1) * RPITCH_D + (c4 >> 1) + 1;
        l32[dw] = p0; l32[dw + 1] = p1;
    }
    __syncthreads();

    float a_ = angles[a];
    float cs = cosf(a_), sn = sinf(a_);
    int lane = tid & 63, w = tid >> 6;   // 16 waves
    int s8 = lane & 7, t8 = lane >> 3;   // 8x8 patch coords
    int sA = w * 16 + s8;                // this thread's two s rows: sA, sA+8
    float scA = (float)sA - 127.5f;
    float tc0 = (float)t8 - 127.5f;
    // row = s*sn + t*cs + c; col = s*cs - t*sn + c
    float rowA = scA * sn + tc0 * cs + 127.5f;
    float colA = scA * cs - tc0 * sn + 127.5f;
    float rowB = rowA + 8.0f * sn;
    float colB = colA + 8.0f * cs;
    float cs8 = 8.0f * cs, sn8 = 8.0f * sn;
    float accA = 0.0f, accB = 0.0f;
    #pragma unroll 4
    for (int j = 0; j < 32; ++j) {       // t = t8 + 8j
        #pragma unroll
        for (int hh = 0; hh < 2; ++hh) {
            float rowv = hh ? rowB : rowA;
            float colv = hh ? colB : colA;
            float fr = floorf(rowv), fc = floorf(colv);
            float wr = rowv - fr, wc = colv - fc;
            int i0 = (int)fr, j0 = (int)fc;
            bool valid = (rowv > -1.0f) & (rowv < 256.0f) & (colv > -1.0f) & (colv < 256.0f);
            int i0c = min(max(i0, -1), 255);
            int j0c = min(max(j0, -1), 255);
            int ca = j0c + 2;
            int ka = ca >> 1;
            int sh = (ca & 1) << 4;
            int dw = (i0c + 1) * RPITCH_D + ka;
            u32 A = l32[dw],            C = l32[dw + 1];
            u32 B = l32[dw + RPITCH_D], D = l32[dw + RPITCH_D + 1];
            u32 top = (u32)((((u64)C << 32) | (u64)A) >> sh);
            u32 bot = (u32)((((u64)D << 32) | (u64)B) >> sh);
            float tl = __uint_as_float(top << 16);
            float tr_ = __uint_as_float(top & 0xffff0000u);
            float bl = __uint_as_float(bot << 16);
            float br = __uint_as_float(bot & 0xffff0000u);
            float tv = tl + (tr_ - tl) * wc;
            float bv = bl + (br - bl) * wc;
            float sv = tv + (bv - tv) * wr;
            sv = valid ? sv : 0.0f;
            if (hh) accB += sv; else accA += sv;
        }
        rowA += cs8; colA -= sn8; rowB += cs8; colB -= sn8;
    }
    // reduce over the 8 t8 lanes (stride-8 butterfly)
    accA += __shfl_xor(accA, 8, 64);
    accA += __shfl_xor(accA, 16, 64);
    accA += __shfl_xor(accA, 32, 64);
    accB += __shfl_xor(accB, 8, 64);
    accB += __shfl_xor(accB, 16, 64);
    accB += __shfl_xor(accB, 32, 64);
    if (t8 == 0) { spart[sA] = accA; spart[sA + 8] = accB; }
    __syncthreads();
    if (tid < 256)
        srow[tid] = spart[tid] - xsino[ra * 256 + tid];
    __syncthreads();
    {   // 511-tap filter, split 4 ways over taps
        int s = tid & 255, q = tid >> 8;
        float fa = 0.0f;
        int m0 = q * 64;
        #pragma unroll 8
        for (int m = m0; m < m0 + 64; ++m) fa += srow[m] * staps[s - m + 255];
        spart[tid] = fa;
    }
    __syncthreads();
    if (tid < 256)
        ws[OFF_FILT + ra * 256 + tid] =
            spart[tid] + spart[tid + 256] + spart[tid + 512] + spart[tid + 768];
}

// =========== K_B: backprojection + y_upd out + conv1 -> h1p ===========
// One block per (b, 2-row tile): 512 blocks x 512 thr, LDS ~60KB -> 2 blocks/CU
// (16 waves). Backproj: 2 interleaved row-chains/thread. Conv1: wave-stationary
// oc (4 oc/wave, 72 weights in VGPRs); y_concat tile staged in LDS.
__global__ __launch_bounds__(512, 4) void k_B(const float* __restrict__ angles,
                                              const float* __restrict__ yprev,
                                              const float* __restrict__ yconc,
                                              const float* __restrict__ stepp,
                                              const float* __restrict__ w1,
                                              const float* __restrict__ b1,
                                              float* __restrict__ ws,
                                              float* __restrict__ dout) {
    __shared__ float sf[NANG * 256];     // 51.2 KB filtered sinogram (batch b)
    __shared__ float supd[4][258];       // y_upd rows y0-1..y0+2 (+col halo)
    __shared__ float sy2[4][258];        // y_concat rows y0-1..y0+2 (+col halo)
    __shared__ float scs[NANG], ssn[NANG];
    int tid = threadIdx.x;
    int b = blockIdx.x >> 7, tile = blockIdx.x & 127;
    int y0 = tile << 1;

    {   // stage sf via float4
        const float4* s4 = (const float4*)(ws + OFF_FILT + b * (NANG * 256));
        float4* d4 = (float4*)sf;
        for (int idx = tid; idx < NANG * 64; idx += 512) d4[idx] = s4[idx];
    }
    if (tid < NANG) {
        float a_ = angles[tid];
        scs[tid] = cosf(a_); ssn[tid] = sinf(a_);
    }
    if (tid < 8) supd[tid >> 1][(tid & 1) * 257] = 0.0f;
    // stage y_concat halo tile
    for (int idx = tid; idx < 4 * 258; idx += 512) {
        int r = idx / 258, x = idx % 258;
        int iy = y0 - 1 + r, ix = x - 1;
        sy2[r][x] = ((unsigned)iy < 256u && (unsigned)ix < 256u)
                        ? yconc[b * PIX + iy * 256 + ix] : 0.0f;
    }
    // zero h1p borders (this block's share: 9 border px * 16 dwords)
    if (tid < 144) {
        int px_i = tile * 9 + (tid >> 4), dw = tid & 15;
        if (px_i < 1028) {
            int y, x;
            if (px_i < 516) { y = (px_i < 258) ? 0 : 257; x = px_i % 258; }
            else            { int j = px_i - 516; y = 1 + (j >> 1); x = (j & 1) * 257; }
            u32* p = (u32*)((u16*)(ws + OFF_H1P) + b * PB + (y * PROW + x) * NCNN);
            p[dw] = 0;
        }
    }
    __syncthreads();

    float step = stepp[0];
    // backproject 4 rows x 256 cols: thread owns col j, rows r0, r0+2
    {
        int j = tid & 255, r0 = tid >> 8;         // r0 in {0,1}
        float xx = (float)j - 127.5f;
        float yy0 = (float)(y0 - 1 + r0) - 127.5f;
        float acc[2] = {0.0f, 0.0f};
        #pragma unroll 5
        for (int a = 0; a < NANG; ++a) {
            float cs = scs[a], sn = ssn[a];
            float f0 = xx * cs + yy0 * sn + 127.5f;
            float idxf[2] = {f0, f0 + sn + sn};
            #pragma unroll
            for (int k = 0; k < 2; ++k) {
                float fl = floorf(idxf[k]);
                int i0 = (int)fl;
                i0 = min(max(i0, 0), 254);
                float w = idxf[k] - (float)i0;
                float v = sf[a * 256 + i0] * (1.0f - w) + sf[a * 256 + i0 + 1] * w;
                acc[k] += (idxf[k] >= 0.0f && idxf[k] <= 255.0f) ? v : 0.0f;
            }
        }
        #pragma unroll
        for (int k = 0; k < 2; ++k) {
            int r = r0 + 2 * k;
            int iy = y0 - 1 + r;
            float val = 0.0f;
            if ((unsigned)iy < 256u) {
                float yy = (float)iy - 127.5f;
                float m = (xx * xx + yy * yy <= 16384.0f) ? 1.0f : 0.0f;
                val = yprev[b * PIX + iy * 256 + j] + step * acc[k] * m;
                if (r >= 1 && r <= 2)
                    dout[NPIX + b * PIX + iy * 256 + j] = val;   // second output
            }
            supd[r][j + 1] = val;
        }
    }
    __syncthreads();

    // conv1 (2->32) + relu: wave w owns oc [4w, 4w+4); weights in VGPRs
    {
        int wave = tid >> 6, lane = tid & 63;
        int oc0 = wave * 4;
        float W[72];
        const float4* wsrc = (const float4*)(w1 + oc0 * 18);
        #pragma unroll
        for (int i = 0; i < 18; ++i) ((float4*)W)[i] = wsrc[i];
        float bb0 = b1[oc0], bb1 = b1[oc0 + 1], bb2 = b1[oc0 + 2], bb3 = b1[oc0 + 3];
        u16* h1base = (u16*)(ws + OFF_H1P) + b * PB;
        #pragma unroll
        for (int it = 0; it < 8; ++it) {
            int px = it * 64 + lane;
            int rr = px >> 8, x = px & 255;
            int oy = y0 + rr;
            float v[18];
            #pragma unroll
            for (int ky = 0; ky < 3; ++ky)
                #pragma unroll
                for (int kx = 0; kx < 3; ++kx) {
                    v[ky * 3 + kx]     = supd[rr + ky][x + kx];
                    v[9 + ky * 3 + kx] = sy2[rr + ky][x + kx];
                }
            float a0 = bb0, a1 = bb1, a2 = bb2, a3 = bb3;
            #pragma unroll
            for (int t = 0; t < 18; ++t) {
                a0 += v[t] * W[t];
                a1 += v[t] * W[18 + t];
                a2 += v[t] * W[36 + t];
                a3 += v[t] * W[54 + t];
            }
            u32 p0 = (u32)f2bf(fmaxf(a0, 0.0f)) | ((u32)f2bf(fmaxf(a1, 0.0f)) << 16);
            u32 p1 = (u32)f2bf(fmaxf(a2, 0.0f)) | ((u32)f2bf(fmaxf(a3, 0.0f)) << 16);
            u32* op = (u32*)(h1base + ((oy + 1) * PROW + (x + 1)) * NCNN + oc0);
            op[0] = p0; op[1] = p1;
        }
    }
}

// =========== K_C: conv2 (MFMA) -> LDS h2 tile + conv3 -> out ===========
// One block per (b, 2-row tile): 512 blocks x 512 thr, LDS ~71KB -> 2 blocks/CU.
#define H2PITCH 34               // u16 per px slot (32 ch + 2 pad) = 17 dwords
__global__ __launch_bounds__(512, 4) void k_C(const float* __restrict__ b2,
                                              const float* __restrict__ w3,
                                              const float* __restrict__ b3,
                                              float* __restrict__ ws,
                                              float* __restrict__ dout) {
    __shared__ u16 sh2[4 * 258 * H2PITCH];   // 70,176 B
    __shared__ u32 swp[9 * 16];              // w3 packed bf16 ch-pairs [t][kd]
    u32* l32 = (u32*)sh2;
    int tid = threadIdx.x;
    int b = blockIdx.x >> 7, tile = blockIdx.x & 127;
    int y0 = tile << 1;

    if (tid < 144) {
        int t = tid >> 4, kd = tid & 15;
        swp[tid] = (u32)f2bf(w3[(2 * kd) * 9 + t]) | ((u32)f2bf(w3[(2 * kd + 1) * 9 + t]) << 16);
    }
    // zero border px columns (stored px 0 and 257) of all 4 rows
    if (tid < 136) {
        int r = tid / 34, rem = tid % 34;
        int col = (rem < 17) ? 0 : 257, dw = rem % 17;
        l32[(r * 258 + col) * 17 + dw] = 0;
    }
    // zero out-of-image rows (edge tiles only)
    #pragma unroll
    for (int r = 0; r < 4; ++r) {
        int hy = y0 - 1 + r;
        if (hy < 0 || hy > 255)
            for (int idx = tid; idx < 258 * 17; idx += 512)
                l32[r * 258 * 17 + idx] = 0;
    }
    __syncthreads();

    // ---- conv2 MFMA: 64 (row, 16px) tiles over 8 waves, pipelined A loads ----
    const u16* __restrict__ w2bf = (const u16*)(ws + OFF_W2BF);
    const u16* __restrict__ h1b  = (const u16*)(ws + OFF_H1P) + b * PB;
    int wave = tid >> 6, lane = tid & 63;
    int m = lane & 15, quad = lane >> 4;
    bfrag Bf[9][2];
    #pragma unroll
    for (int t = 0; t < 9; ++t) {
        const u16* wp = w2bf + t * 1024 + m * 32 + quad * 8;
        Bf[t][0] = *(const bfrag*)(wp);
        Bf[t][1] = *(const bfrag*)(wp + 16 * 32);
    }
    float bias0 = b2[m], bias1 = b2[m + 16];
    #pragma unroll
    for (int k = 0; k < 8; ++k) {
        int tl = wave + (k << 3);        // 0..63
        int ridx = tl >> 4, xt = tl & 15;
        int hy = y0 - 1 + ridx;
        bool valid = (unsigned)hy < 256u;
        int hyc = min(max(hy, 0), 255);
        int xs = xt << 4;
        bfrag A0[3], A1[3];
        #pragma unroll
        for (int tx = 0; tx < 3; ++tx)
            A0[tx] = *(const bfrag*)(h1b + ((hyc + 0) * PROW + xs + m + tx) * NCNN + quad * 8);
        #pragma unroll
        for (int tx = 0; tx < 3; ++tx)
            A1[tx] = *(const bfrag*)(h1b + ((hyc + 1) * PROW + xs + m + tx) * NCNN + quad * 8);
        ffrag c0 = {0.f, 0.f, 0.f, 0.f}, c1 = {0.f, 0.f, 0.f, 0.f};
        #pragma unroll
        for (int tx = 0; tx < 3; ++tx) {
            c0 = __builtin_amdgcn_mfma_f32_16x16x32_bf16(A0[tx], Bf[tx][0], c0, 0, 0, 0);
            c1 = __builtin_amdgcn_mfma_f32_16x16x32_bf16(A0[tx], Bf[tx][1], c1, 0, 0, 0);
        }
        #pragma unroll
        for (int tx = 0; tx < 3; ++tx)
            A0[tx] = *(const bfrag*)(h1b + ((hyc + 2) * PROW + xs + m + tx) * NCNN + quad * 8);
        #pragma unroll
        for (int tx = 0; tx < 3; ++tx) {
            c0 = __builtin_amdgcn_mfma_f32_16x16x32_bf16(A1[tx], Bf[3 + tx][0], c0, 0, 0, 0);
            c1 = __builtin_amdgcn_mfma_f32_16x16x32_bf16(A1[tx], Bf[3 + tx][1], c1, 0, 0, 0);
        }
        #pragma unroll
        for (int tx = 0; tx < 3; ++tx) {
            c0 = __builtin_amdgcn_mfma_f32_16x16x32_bf16(A0[tx], Bf[6 + tx][0], c0, 0, 0, 0);
            c1 = __builtin_amdgcn_mfma_f32_16x16x32_bf16(A0[tx], Bf[6 + tx][1], c1, 0, 0, 0);
        }
        if (valid) {
            #pragma unroll
            for (int r = 0; r < 4; ++r) {
                int px = xs + quad * 4 + r;
                u16* op = sh2 + (ridx * 258 + px + 1) * H2PITCH;
                op[m]      = f2bf(fmaxf(c0[r] + bias0, 0.0f));
                op[m + 16] = f2bf(fmaxf(c1[r] + bias1, 0.0f));
            }
        }
    }
    __syncthreads();

    // ---- conv3 (32->1): one px per thread ----
    {
        int rr = tid >> 8, x = tid & 255;
        int oy = y0 + rr;
        float acc = b3[0];
        #pragma unroll
        for (int ky = 0; ky < 3; ++ky) {
            #pragma unroll
            for (int cx = 0; cx < 3; ++cx) {
                int t = ky * 3 + cx;
                const u32* q = l32 + ((rr + ky) * 258 + x + cx) * 17;
                #pragma unroll
                for (int kd = 0; kd < 16; ++kd) {
                    u32 hv = q[kd];
                    u32 wv = swp[t * 16 + kd];
                    float h0 = __uint_as_float(hv << 16);
                    float h1 = __uint_as_float(hv & 0xffff0000u);
                    float w0 = __uint_as_float(wv << 16);
                    float w1_ = __uint_as_float(wv & 0xffff0000u);
                    acc += h0 * w0 + h1 * w1_;
                }
            }
        }
        dout[b * PIX + oy * 256 + x] = acc;    // first output
    }
}

extern "C" void kernel_launch(void* const* d_in, const int* in_sizes, int n_in,
                              void* d_out, int out_size, void* d_ws, size_t ws_size,
                              hipStream_t stream) {
    const float* xsino  = (const float*)d_in[0];
    const float* yprev  = (const float*)d_in[1];
    const float* yconc  = (const float*)d_in[2];
    const float* angles = (const float*)d_in[3];
    const float* stepp  = (const float*)d_in[4];
    const float* w1 = (const float*)d_in[5];
    const float* b1 = (const float*)d_in[6];
    const float* w2 = (const float*)d_in[7];
    const float* b2 = (const float*)d_in[8];
    const float* w3 = (const float*)d_in[9];
    const float* b3 = (const float*)d_in[10];
    float* out = (float*)d_out;
    float* ws  = (float*)d_ws;

    k_A<<<209, 1024, 0, stream>>>(angles, yprev, xsino, w2, ws);
    k_B<<<BATCH * 128, 512, 0, stream>>>(angles, yprev, yconc, stepp, w1, b1, ws, out);
    k_C<<<BATCH * 128, 512, 0, stream>>>(b2, w3, b3, ws, out);
}